// Round 1
// baseline (159.643 us; speedup 1.0000x reference)
//
#include <hip/hip_runtime.h>
#include <hip/hip_fp16.h>

#define D_VOCAB 262
#define D_EMB   128
#define KW      5
#define NCHAR   16

// ---------------------------------------------------------------------------
// Kernel 1: P[v][k][o] = sum_i emb[v][i] * conv_w[o][i][k], stored as fp16.
// Layout: P[(v*KW + k)*D_EMB + o]  -> per-id block of 5*128 halfs = 1280 B,
// contiguous, so the main kernel's 5 k-row reads for one id are one 1280 B
// region (L2-friendly).
// Grid: 262 blocks (v) x 640 threads (t = k*128 + o). ~21 MFLOP total.
// ---------------------------------------------------------------------------
__global__ __launch_bounds__(640) void precompute_P_kernel(
    const float* __restrict__ emb, const float* __restrict__ conv_w,
    __half* __restrict__ P) {
  __shared__ float emb_s[D_EMB];
  const int v = blockIdx.x;
  const int t = threadIdx.x;
  if (t < D_EMB) emb_s[t] = emb[v * D_EMB + t];
  __syncthreads();

  const int k = t >> 7;    // 0..4  (wave-uniform: each wave spans one k)
  const int o = t & 127;
  // conv_w layout (O, I, K): [o][i][k] -> o*(128*5) + i*5 + k
  const float* w = conv_w + o * (D_EMB * KW) + k;
  float acc = 0.f;
#pragma unroll 8
  for (int i = 0; i < D_EMB; ++i) {
    acc += emb_s[i] * w[i * KW];
  }
  P[(v * KW + k) * D_EMB + o] = __float2half(acc);
}

// ---------------------------------------------------------------------------
// Kernel 2: one wave per sequence (n). 128 out-channels -> 2 per lane.
// y[c][o] = sum over j in [c-2, c+2] of P[j-c+2][id[j]][o]; out = b + max_c y.
// Contribution form: id[j] with table k adds into c = j + 2 - k.
// ids are wave-uniform -> readfirstlane(n) so the compiler emits s_load for
// the id and keeps the P row base in SGPRs (vector offset = lane only).
// ---------------------------------------------------------------------------
__global__ __launch_bounds__(256) void conv_char_main_kernel(
    const int* __restrict__ ids, const __half* __restrict__ P,
    const float* __restrict__ bias, float* __restrict__ out) {
  const int lane = threadIdx.x & 63;
  int n = (int)((blockIdx.x * blockDim.x + threadIdx.x) >> 6);
  n = __builtin_amdgcn_readfirstlane(n);  // wave-uniform sequence index

  const int* idrow = ids + n * NCHAR;
  const int oofs = lane * 2;  // this lane's first out-channel

  float2 y[NCHAR];
#pragma unroll
  for (int c = 0; c < NCHAR; ++c) { y[c].x = 0.f; y[c].y = 0.f; }

#pragma unroll
  for (int j = 0; j < NCHAR; ++j) {
    const int id = idrow[j];                       // scalar load (uniform)
    const __half* row = P + (size_t)id * (KW * D_EMB) + oofs;
#pragma unroll
    for (int k = 0; k < KW; ++k) {
      const int c = j + 2 - k;
      if (c >= 0 && c < NCHAR) {
        const __half2 h = *(const __half2*)(row + k * D_EMB);
        const float2 v = __half22float2(h);
        y[c].x += v.x;
        y[c].y += v.y;
      }
    }
  }

  float2 m = y[0];
#pragma unroll
  for (int c = 1; c < NCHAR; ++c) {
    m.x = fmaxf(m.x, y[c].x);
    m.y = fmaxf(m.y, y[c].y);
  }

  const float2 b = *(const float2*)(bias + oofs);
  float2 r;
  r.x = m.x + b.x;
  r.y = m.y + b.y;
  *(float2*)(out + (size_t)n * D_EMB + oofs) = r;
}

// ---------------------------------------------------------------------------
// Inputs (setup_inputs order):
//   d_in[0] input    (B*W*C)   int32   (ids, values < 262)
//   d_in[1] lengths  (B*W)     int32   (UNUSED by the reference)
//   d_in[2] emb_weight (262*128) float32
//   d_in[3] conv_w   (128*128*5) float32
//   d_in[4] conv_b   (128)       float32
// Output: (B*W*128) float32.
// Workspace: P table = 262*5*128 halfs = 335,360 bytes.
// ---------------------------------------------------------------------------
extern "C" void kernel_launch(void* const* d_in, const int* in_sizes, int n_in,
                              void* d_out, int out_size, void* d_ws, size_t ws_size,
                              hipStream_t stream) {
  const int*   input = (const int*)d_in[0];
  const float* emb   = (const float*)d_in[2];
  const float* cw    = (const float*)d_in[3];
  const float* cb    = (const float*)d_in[4];
  float* out = (float*)d_out;
  __half* P = (__half*)d_ws;  // 335,360 B needed

  const int n_seq = in_sizes[0] / NCHAR;  // B*W = 32768

  precompute_P_kernel<<<D_VOCAB, 640, 0, stream>>>(emb, cw, P);

  const int waves_per_block = 4;                    // 256 threads
  const int blocks = n_seq / waves_per_block;       // 8192
  conv_char_main_kernel<<<blocks, 256, 0, stream>>>(input, P, cb, out);
}

// Round 2
// 132.439 us; speedup vs baseline: 1.2054x; 1.2054x over previous
//
#include <hip/hip_runtime.h>
#include <hip/hip_fp16.h>

#define D_VOCAB 262
#define D_EMB   128
#define KW      5
#define NCHAR   16

// P layout: P[v*640 + k*128 + o]  (fp16). Per-id block = 1280 B contiguous.

// ---------------------------------------------------------------------------
// Kernel 1: P[v][k][o] = sum_i emb[v][i] * conv_w[o][i][k].
// One block per v, 640 threads (t = c = k*128+o). conv_w is read with
// coalesced float4 loads and transposed through LDS (i-tiles of 16), so the
// inner product reads LDS conflict-free instead of stride-2560B global.
// Row stride 644 (pad +4) spreads the scattered ds_writes across banks.
// ---------------------------------------------------------------------------
#define WROW 644
__global__ __launch_bounds__(640) void precompute_P_kernel(
    const float* __restrict__ emb, const float* __restrict__ conv_w,
    __half* __restrict__ P) {
  __shared__ float emb_s[D_EMB];
  __shared__ float w_s[16 * WROW];   // 41,216 B
  const int v = blockIdx.x;
  const int t = threadIdx.x;
  if (t < D_EMB) emb_s[t] = emb[v * D_EMB + t];

  float acc = 0.f;
  for (int i0 = 0; i0 < D_EMB; i0 += 16) {
    __syncthreads();  // previous tile's reads done (also covers emb_s write)
    // stage 16 i-rows of conv_w, transposed: w_s[ii*WROW + k*128 + o]
    // source: conv_w[o*640 + (i0+ii)*5 + k]; per-o chunk = 80 floats.
#pragma unroll
    for (int it = 0; it < 4; ++it) {
      const int idx = t + it * 640;            // 0..2559 float4 index
      const int o   = idx / 20;                // 20 float4 per o-chunk
      const int r4  = idx % 20;
      const float4 wv = *(const float4*)(conv_w + o * (D_EMB * KW) + i0 * KW + r4 * 4);
      const float elems[4] = {wv.x, wv.y, wv.z, wv.w};
#pragma unroll
      for (int e = 0; e < 4; ++e) {
        const int r  = r4 * 4 + e;             // 0..79 within chunk
        const int ii = r / KW;
        const int k  = r % KW;
        w_s[ii * WROW + k * D_EMB + o] = elems[e];
      }
    }
    __syncthreads();
#pragma unroll
    for (int ii = 0; ii < 16; ++ii) {
      acc += emb_s[i0 + ii] * w_s[ii * WROW + t];
    }
  }
  P[v * (KW * D_EMB) + t] = __float2half(acc);
}

// ---------------------------------------------------------------------------
// Kernel 2: 4 sequences per wave; 16 lanes/seq; 8 channels/lane.
// P loads are float4 (16 B/lane, 1 KB per wave-instruction).
// Rolling 5-slot accumulator window + fused max keeps VGPRs at ~48 acc regs.
//   y[c][o] = sum_k P[id[c+2-k... ]] : id at position j contributes to
//   c = j+2-k with table row k; y[c] completes after j = c+2.
// ---------------------------------------------------------------------------
__global__ __launch_bounds__(256) void conv_char_main_kernel(
    const int* __restrict__ ids, const __half* __restrict__ P,
    const float* __restrict__ bias, float* __restrict__ out) {
  const int lane = threadIdx.x & 63;
  const int wave = threadIdx.x >> 6;
  const int n_base = (blockIdx.x * 4 + wave) * 4;  // 4 seqs per wave
  const int g = lane >> 4;                          // seq within wave
  const int s = lane & 15;
  const int o = s * 8;                              // this lane's 8 channels
  const int n = n_base + g;

  // preload the wave's 64 ids (4 seqs x 16 chars), coalesced
  const int myid = ids[n_base * NCHAR + lane];
  const int src_base = lane & 48;                   // g*16

  float win[5][8];
#pragma unroll
  for (int w = 0; w < 5; ++w)
#pragma unroll
    for (int e = 0; e < 8; ++e) win[w][e] = 0.f;
  float vmax[8];
#pragma unroll
  for (int e = 0; e < 8; ++e) vmax[e] = -1e30f;

#pragma unroll
  for (int j = 0; j < NCHAR; ++j) {
    const int id = __shfl(myid, src_base + j);      // broadcast within group
    const __half* row = P + (size_t)id * (KW * D_EMB) + o;
#pragma unroll
    for (int k = 0; k < KW; ++k) {
      const int c = j + 2 - k;
      if (c >= 0 && c < NCHAR) {
        const float4 f4 = *(const float4*)(row + k * D_EMB);  // 8 halfs
        const __half2* h2 = (const __half2*)&f4;
        float* acc = win[c % 5];
#pragma unroll
        for (int q = 0; q < 4; ++q) {
          const float2 v = __half22float2(h2[q]);
          acc[q * 2]     += v.x;
          acc[q * 2 + 1] += v.y;
        }
      }
    }
    if (j >= 2) {                                   // y[j-2] is complete
      float* w = win[(j - 2) % 5];
#pragma unroll
      for (int e = 0; e < 8; ++e) { vmax[e] = fmaxf(vmax[e], w[e]); w[e] = 0.f; }
    }
  }
#pragma unroll
  for (int c = 14; c < 16; ++c) {
    const float* w = win[c % 5];
#pragma unroll
    for (int e = 0; e < 8; ++e) vmax[e] = fmaxf(vmax[e], w[e]);
  }

  const float4 b0 = *(const float4*)(bias + o);
  const float4 b1 = *(const float4*)(bias + o + 4);
  float4 r0, r1;
  r0.x = vmax[0] + b0.x; r0.y = vmax[1] + b0.y;
  r0.z = vmax[2] + b0.z; r0.w = vmax[3] + b0.w;
  r1.x = vmax[4] + b1.x; r1.y = vmax[5] + b1.y;
  r1.z = vmax[6] + b1.z; r1.w = vmax[7] + b1.w;
  float* op = out + (size_t)n * D_EMB + o;
  *(float4*)(op)     = r0;
  *(float4*)(op + 4) = r1;
}

// ---------------------------------------------------------------------------
// Inputs: d_in[0] ids (B*W*C int32), d_in[1] lengths (unused),
//         d_in[2] emb (262x128 f32), d_in[3] conv_w (128x128x5 f32),
//         d_in[4] conv_b (128 f32).  Output: (B*W*128) f32.
// Workspace: P = 262*5*128 halfs = 335,360 B.
// ---------------------------------------------------------------------------
extern "C" void kernel_launch(void* const* d_in, const int* in_sizes, int n_in,
                              void* d_out, int out_size, void* d_ws, size_t ws_size,
                              hipStream_t stream) {
  const int*   input = (const int*)d_in[0];
  const float* emb   = (const float*)d_in[2];
  const float* cw    = (const float*)d_in[3];
  const float* cb    = (const float*)d_in[4];
  float* out = (float*)d_out;
  __half* P = (__half*)d_ws;

  const int n_seq = in_sizes[0] / NCHAR;   // B*W = 32768

  precompute_P_kernel<<<D_VOCAB, 640, 0, stream>>>(emb, cw, P);

  // 4 waves/block, 4 seqs/wave -> 16 seqs/block
  const int blocks = n_seq / 16;           // 2048
  conv_char_main_kernel<<<blocks, 256, 0, stream>>>(input, P, cb, out);
}

// Round 4
// 104.962 us; speedup vs baseline: 1.5210x; 1.2618x over previous
//
#include <hip/hip_runtime.h>
#include <hip/hip_fp16.h>

#define D_VOCAB 262
#define D_EMB   128
#define KW      5
#define NCHAR   16
#define NKO     (KW * D_EMB)      // 640 (k,o) pairs

typedef _Float16 h8 __attribute__((ext_vector_type(8)));
typedef float    f8 __attribute__((ext_vector_type(8)));

// d_ws layout:
//   P  at offset 0       : 262*640 halfs = 335,360 B   (fp16 lookup table)
//   Wt at offset 335,872 : 640*128 floats = 327,680 B  (transposed conv_w)

// ---------------------------------------------------------------------------
// Stage 1: Wt[(k*128+o)*128 + i] = conv_w[o*640 + i*5 + k].
// Coalesced dword reads, scattered dword writes (320 KB, L2 absorbs).
// ---------------------------------------------------------------------------
__global__ __launch_bounds__(256) void transpose_w_kernel(
    const float* __restrict__ cw, float* __restrict__ Wt) {
  const int gid = blockIdx.x * 256 + threadIdx.x;   // 0..81919
  const float val = cw[gid];
  const int o = gid / 640;
  const int r = gid - o * 640;
  const int i = r / 5;
  const int k = r - i * 5;
  Wt[(k * D_EMB + o) * D_EMB + i] = val;
}

// ---------------------------------------------------------------------------
// Stage 2: P[v][ko] = sum_i emb[v][i] * Wt[ko][i], stored fp16.
// One lane per output: 32 independent float4 loads of L2-resident Wt rows +
// 128 FMA; emb row is wave-uniform (scalar loads). 2620 waves, no barriers.
// ---------------------------------------------------------------------------
__global__ __launch_bounds__(256) void compute_P_kernel(
    const float* __restrict__ emb, const float* __restrict__ Wt,
    _Float16* __restrict__ P) {
  const int wave = threadIdx.x >> 6;
  const int lane = threadIdx.x & 63;
  const int w = blockIdx.x * 4 + wave;      // 0..2619
  const int v = w / 10;                     // vocab id (wave-uniform)
  const int ko = (w - v * 10) * 64 + lane;  // this lane's (k,o) row

  const float* er = emb + v * D_EMB;
  const float4* wt = (const float4*)(Wt + ko * D_EMB);
  float acc = 0.f;
#pragma unroll 8
  for (int i4 = 0; i4 < 32; ++i4) {
    const float4 wv = wt[i4];
    acc += er[i4 * 4 + 0] * wv.x + er[i4 * 4 + 1] * wv.y +
           er[i4 * 4 + 2] * wv.z + er[i4 * 4 + 3] * wv.w;
  }
  P[v * NKO + ko] = (_Float16)acc;
}

// ---------------------------------------------------------------------------
// Main: 4 seqs/wave, 16 lanes/seq, 8 channels/lane (16 B float4 = 8 halfs).
// Packed-fp16 accumulate (v_pk_add_f16) + packed max (v_pk_max_f16): 4 VALU
// per load, half the accumulator VGPRs of fp32 -> higher occupancy to hide
// L2 latency. Rolling 5-slot window, fused max; fp32 bias+store epilogue.
// ---------------------------------------------------------------------------
__global__ __launch_bounds__(256) void conv_char_main_kernel(
    const int* __restrict__ ids, const _Float16* __restrict__ P,
    const float* __restrict__ bias, float* __restrict__ out) {
  const int lane = threadIdx.x & 63;
  const int wave = threadIdx.x >> 6;
  const int n_base = (blockIdx.x * 4 + wave) * 4;  // 4 seqs per wave
  const int g4 = lane & 48;                        // seq-group * 16
  const int s = lane & 15;
  const int o = s * 8;                             // this lane's 8 channels
  const int n = n_base + (lane >> 4);

  // the wave's 64 ids (4 seqs x 16 chars), coalesced
  const int myid = ids[n_base * NCHAR + lane];

  h8 win[5];
#pragma unroll
  for (int w = 0; w < 5; ++w) win[w] = (h8)(_Float16)0.f;
  h8 vmax = (h8)(_Float16)(-60000.f);

#pragma unroll
  for (int j = 0; j < NCHAR; ++j) {
    const int id = __shfl(myid, g4 + j);           // broadcast within group
    const _Float16* row = P + (size_t)id * NKO + o;
#pragma unroll
    for (int k = 0; k < KW; ++k) {
      const int c = j + 2 - k;                     // output position fed
      if (c >= 0 && c < NCHAR) {
        const h8 val = *(const h8*)(row + k * D_EMB);   // 16 B load
        win[c % 5] += val;                              // 4x v_pk_add_f16
      }
    }
    if (j >= 2) {                                  // y[j-2] complete
      const int w = (j - 2) % 5;
      vmax = __builtin_elementwise_max(vmax, win[w]);   // 4x v_pk_max_f16
      win[w] = (h8)(_Float16)0.f;
    }
  }
  vmax = __builtin_elementwise_max(vmax, win[14 % 5]);
  vmax = __builtin_elementwise_max(vmax, win[15 % 5]);

  const f8 fv = __builtin_convertvector(vmax, f8);
  const f8 bv = *(const f8*)(bias + o);
  const f8 r = fv + bv;
  *(f8*)(out + (size_t)n * D_EMB + o) = r;
}

// ---------------------------------------------------------------------------
// Inputs: d_in[0] ids (B*W*C int32), d_in[1] lengths (unused),
//         d_in[2] emb (262x128 f32), d_in[3] conv_w (128x128x5 f32),
//         d_in[4] conv_b (128 f32).  Output: (B*W*128) f32.
// ---------------------------------------------------------------------------
extern "C" void kernel_launch(void* const* d_in, const int* in_sizes, int n_in,
                              void* d_out, int out_size, void* d_ws, size_t ws_size,
                              hipStream_t stream) {
  const int*   input = (const int*)d_in[0];
  const float* emb   = (const float*)d_in[2];
  const float* cw    = (const float*)d_in[3];
  const float* cb    = (const float*)d_in[4];
  float* out = (float*)d_out;

  _Float16* P  = (_Float16*)d_ws;
  float*    Wt = (float*)((char*)d_ws + 335872);

  const int n_seq = in_sizes[0] / NCHAR;   // B*W = 32768

  transpose_w_kernel<<<320, 256, 0, stream>>>(cw, Wt);    // 81920 elems
  compute_P_kernel<<<655, 256, 0, stream>>>(emb, Wt, P);  // 2620 waves

  const int blocks = n_seq / 16;           // 4 waves/block, 4 seqs/wave
  conv_char_main_kernel<<<blocks, 256, 0, stream>>>(input, P, cb, out);
}